// Round 2
// 939.801 us; speedup vs baseline: 1.0450x; 1.0450x over previous
//
#include <hip/hip_runtime.h>
#include <hip/hip_bf16.h>
#include <cstdint>

using bf16 = __hip_bfloat16;
typedef __attribute__((ext_vector_type(8))) short short8;
typedef __attribute__((ext_vector_type(4))) short short4v;
typedef __attribute__((ext_vector_type(4))) float floatx4;

#define DEVINL __device__ __forceinline__

DEVINL short bfbits(float v) { return __builtin_bit_cast(short, __float2bfloat16(v)); }

// async global->LDS, 16B per lane. LDS dest must be wave-uniform base + lane*16 (linear).
DEVINL void gload_lds16(const void* g, void* l) {
  __builtin_amdgcn_global_load_lds((const __attribute__((address_space(1))) void*)g,
                                   (__attribute__((address_space(3))) void*)l, 16, 0, 0);
}

template<int ACT> DEVINL float activate(float v) {
  if constexpr (ACT == 1) return v > 0.f ? v : 0.25f * v;            // leaky_relu(0.25)
  else if constexpr (ACT == 2) return v > 0.f ? v : __expf(v) - 1.f; // elu
  else return v;
}

// C[M,N] = A[M,K] * B[N,K]^T (+bias[col]) (+act).  f32 accum, MFMA bf16.
// blockIdx (swizzled) selects view via z, fusing two independent GEMMs.
// AF32: A is float32 -> reg-staged + converted at LDS-write (fallback path).
// !AF32: A,B bf16 -> global_load_lds width-16 double-buffered staging, 1 barrier/K-step.
// TRANS: store C^T (bf16). DUAL (with OF32): also store bf16 C to outB.
// XCD-aware bijective swizzle: each XCD gets a contiguous chunk of blocks so the 8
// blocks sharing an A row-panel hit the SAME L2 (kills the ~4x A over-fetch).
template<int ACT, int TRANS, int BIAS, int AF32, int OF32, int DUAL>
__global__ __launch_bounds__(256, 2)
void gemm_bt(const void* __restrict__ A1, const void* __restrict__ A2, int lda,
             const bf16* __restrict__ B1, const bf16* __restrict__ B2, int ldb,
             const float* __restrict__ bias1, const float* __restrict__ bias2,
             void* __restrict__ out1, void* __restrict__ out2,
             bf16* __restrict__ outB1, bf16* __restrict__ outB2,
             int ldo, int K)
{
  // ---- XCD swizzle (bijective; nwg is always a multiple of 8 here) ----
  const int gx = gridDim.x, gy = gridDim.y;
  const int nwg = gx * gy * gridDim.z;
  int bx, by, vz;
  if (nwg & 7) {
    bx = blockIdx.x; by = blockIdx.y; vz = blockIdx.z;
  } else {
    const int flat = blockIdx.x + gx * (blockIdx.y + gy * blockIdx.z);
    const int cpx = nwg >> 3;
    const int w = (flat & 7) * cpx + (flat >> 3);
    bx = w % gx;
    const int tmp = w / gx;
    by = tmp % gy;
    vz = tmp / gy;
  }

  const void* A = vz ? A2 : A1;
  const bf16* B = vz ? B2 : B1;
  const float* bias = vz ? bias2 : bias1;
  void* out = vz ? out2 : out1;
  bf16* outB = vz ? outB2 : outB1;

  constexpr int NBUF = AF32 ? 1 : 2;
  __shared__ bf16 At[NBUF][128 * 64];
  __shared__ bf16 Bt[NBUF][128 * 64];
  const int t = threadIdx.x;
  const int wave = t >> 6, lane = t & 63;
  const int mBase = by * 128, nBase = bx * 128;
  const int wm = (wave >> 1) * 64, wn = (wave & 1) * 64;
  const int q = lane >> 4, lm = lane & 15;

  floatx4 acc[4][4];
#pragma unroll
  for (int i = 0; i < 4; i++)
#pragma unroll
    for (int j = 0; j < 4; j++) acc[i][j] = (floatx4){0.f, 0.f, 0.f, 0.f};

  if constexpr (!AF32) {
    // ---- global_load_lds double-buffered staging ----
    auto STAGE = [&](int buf, int kb) {
#pragma unroll
      for (int i = 0; i < 4; i++) {
        const int c0 = i * 256 + wave * 64;   // wave-uniform LDS base (elements/8)
        const int c = c0 + lane;
        const bf16* ga = (const bf16*)A + (size_t)(mBase + (c >> 3)) * lda + kb + ((c & 7) << 3);
        const bf16* gb = B + (size_t)(nBase + (c >> 3)) * ldb + kb + ((c & 7) << 3);
        gload_lds16(ga, &At[buf][c0 * 8]);
        gload_lds16(gb, &Bt[buf][c0 * 8]);
      }
    };
    int cur = 0;
    STAGE(0, 0);
    for (int kb = 0; kb < K; kb += 64) {
      __syncthreads();                        // drains vmcnt -> buf[cur] ready; prev readers done
      if (kb + 64 < K) STAGE(cur ^ 1, kb + 64);  // prefetch overlaps MFMA below
#pragma unroll
      for (int ks = 0; ks < 64; ks += 32) {
        short8 af[4], bfr[4];
#pragma unroll
        for (int i = 0; i < 4; i++)
          af[i] = *(const short8*)&At[cur][(wm + i * 16 + lm) * 64 + ks + q * 8];
#pragma unroll
        for (int j = 0; j < 4; j++)
          bfr[j] = *(const short8*)&Bt[cur][(wn + j * 16 + lm) * 64 + ks + q * 8];
#pragma unroll
        for (int i = 0; i < 4; i++)
#pragma unroll
          for (int j = 0; j < 4; j++)
            acc[i][j] = __builtin_amdgcn_mfma_f32_16x16x32_bf16(af[i], bfr[j], acc[i][j], 0, 0, 0);
      }
      cur ^= 1;
    }
  } else {
    // ---- fallback: f32 A, reg-staged, convert at LDS-write ----
    floatx4 apl[4], aph[4];
    short8 bpb[4];
    auto LA = [&](int kb) {
#pragma unroll
      for (int i = 0; i < 4; i++) {
        int c = i * 256 + t;
        size_t off = (size_t)(mBase + (c >> 3)) * lda + kb + ((c & 7) << 3);
        const float* f = (const float*)A + off;
        apl[i] = *(const floatx4*)f;
        aph[i] = *(const floatx4*)(f + 4);
      }
    };
    auto LB = [&](int kb) {
#pragma unroll
      for (int i = 0; i < 4; i++) {
        int c = i * 256 + t;
        bpb[i] = *(const short8*)(B + (size_t)(nBase + (c >> 3)) * ldb + kb + ((c & 7) << 3));
      }
    };
    LA(0); LB(0);
    for (int kb = 0; kb < K; kb += 64) {
      __syncthreads();
#pragma unroll
      for (int i = 0; i < 4; i++) {
        int c = i * 256 + t;
        short8 r;
#pragma unroll
        for (int j = 0; j < 4; j++) { r[j] = bfbits(apl[i][j]); r[4 + j] = bfbits(aph[i][j]); }
        *(short8*)&At[0][c * 8] = r;
        *(short8*)&Bt[0][c * 8] = bpb[i];
      }
      __syncthreads();
      if (kb + 64 < K) { LA(kb + 64); LB(kb + 64); }
#pragma unroll
      for (int ks = 0; ks < 64; ks += 32) {
        short8 af[4], bfr[4];
#pragma unroll
        for (int i = 0; i < 4; i++)
          af[i] = *(const short8*)&At[0][(wm + i * 16 + lm) * 64 + ks + q * 8];
#pragma unroll
        for (int j = 0; j < 4; j++)
          bfr[j] = *(const short8*)&Bt[0][(wn + j * 16 + lm) * 64 + ks + q * 8];
#pragma unroll
        for (int i = 0; i < 4; i++)
#pragma unroll
          for (int j = 0; j < 4; j++)
            acc[i][j] = __builtin_amdgcn_mfma_f32_16x16x32_bf16(af[i], bfr[j], acc[i][j], 0, 0, 0);
      }
    }
  }

#pragma unroll
  for (int i = 0; i < 4; i++) {
#pragma unroll
    for (int j = 0; j < 4; j++) {
      const int col = nBase + wn + j * 16 + lm;
      float bv2 = 0.f;
      if constexpr (BIAS) bv2 = bias[col];
      if constexpr (TRANS) {
        short4v pk;
#pragma unroll
        for (int r = 0; r < 4; r++)
          pk[r] = bfbits(activate<ACT>(acc[i][j][r] + bv2));
        const int row = mBase + wm + i * 16 + q * 4;
        *(short4v*)&((bf16*)out)[(size_t)col * ldo + row] = pk;
      } else {
#pragma unroll
        for (int r = 0; r < 4; r++) {
          const int row = mBase + wm + i * 16 + q * 4 + r;
          float v = activate<ACT>(acc[i][j][r] + bv2);
          if constexpr (OF32) ((float*)out)[(size_t)row * ldo + col] = v;
          else ((bf16*)out)[(size_t)row * ldo + col] = __float2bfloat16(v);
          if constexpr (DUAL) outB[(size_t)row * ldo + col] = __float2bfloat16(v);
        }
      }
    }
  }
}

// Fused 3-way sim reduction: blockIdx.z = 0:(n1,n1->R11) 1:(n2,n2->R22) 2:(n1,n2->R12,C12).
__global__ __launch_bounds__(256, 2)
void sim3(const bf16* __restrict__ n1, const bf16* __restrict__ n2,
          float* __restrict__ R11, float* __restrict__ R22,
          float* __restrict__ R12, float* __restrict__ C12)
{
  const bf16 *A, *B; float *Rs, *Cs;
  if (blockIdx.z == 0)      { A = n1; B = n1; Rs = R11; Cs = nullptr; }
  else if (blockIdx.z == 1) { A = n2; B = n2; Rs = R22; Cs = nullptr; }
  else                      { A = n1; B = n2; Rs = R12; Cs = C12; }

  __shared__ bf16 At[128 * 64];
  __shared__ bf16 Bt[128 * 64];
  const int t = threadIdx.x;
  const int wave = t >> 6, lane = t & 63;
  const int mBase = blockIdx.y * 128, nBase = blockIdx.x * 128;
  const int wm = (wave >> 1) * 64, wn = (wave & 1) * 64;
  const int q = lane >> 4, lm = lane & 15;

  floatx4 acc[4][4];
#pragma unroll
  for (int i = 0; i < 4; i++)
#pragma unroll
    for (int j = 0; j < 4; j++) acc[i][j] = (floatx4){0.f, 0.f, 0.f, 0.f};

  short8 apb[4], bpb[4];
  auto LD = [&](int kb) {
#pragma unroll
    for (int i = 0; i < 4; i++) {
      int c = i * 256 + t;
      apb[i] = *(const short8*)(A + (size_t)(mBase + (c >> 3)) * 256 + kb + ((c & 7) << 3));
      bpb[i] = *(const short8*)(B + (size_t)(nBase + (c >> 3)) * 256 + kb + ((c & 7) << 3));
    }
  };

  LD(0);
  for (int kb = 0; kb < 256; kb += 64) {
    __syncthreads();
#pragma unroll
    for (int i = 0; i < 4; i++) {
      int c = i * 256 + t;
      *(short8*)&At[c * 8] = apb[i];
      *(short8*)&Bt[c * 8] = bpb[i];
    }
    __syncthreads();
    if (kb + 64 < 256) LD(kb + 64);
#pragma unroll
    for (int ks = 0; ks < 64; ks += 32) {
      short8 af[4], bfr[4];
#pragma unroll
      for (int i = 0; i < 4; i++)
        af[i] = *(const short8*)&At[(wm + i * 16 + lm) * 64 + ks + q * 8];
#pragma unroll
      for (int j = 0; j < 4; j++)
        bfr[j] = *(const short8*)&Bt[(wn + j * 16 + lm) * 64 + ks + q * 8];
#pragma unroll
      for (int i = 0; i < 4; i++)
#pragma unroll
        for (int j = 0; j < 4; j++)
          acc[i][j] = __builtin_amdgcn_mfma_f32_16x16x32_bf16(af[i], bfr[j], acc[i][j], 0, 0, 0);
    }
  }

  float rs[4][4], cs[4];
#pragma unroll
  for (int i = 0; i < 4; i++) { cs[i] = 0.f;
#pragma unroll
    for (int r = 0; r < 4; r++) rs[i][r] = 0.f; }

#pragma unroll
  for (int i = 0; i < 4; i++)
#pragma unroll
    for (int j = 0; j < 4; j++)
#pragma unroll
      for (int r = 0; r < 4; r++) {
        float e = __expf(2.f * acc[i][j][r]);   // 1/TAU = 2
        rs[i][r] += e;
        cs[j] += e;
      }

#pragma unroll
  for (int i = 0; i < 4; i++)
#pragma unroll
    for (int r = 0; r < 4; r++) {
      float v = rs[i][r];
      v += __shfl_xor(v, 1); v += __shfl_xor(v, 2);
      v += __shfl_xor(v, 4); v += __shfl_xor(v, 8);
      if (lm == 0) atomicAdd(&Rs[mBase + wm + i * 16 + q * 4 + r], v);
    }
  if (Cs) {
#pragma unroll
    for (int j = 0; j < 4; j++) {
      float v = cs[j];
      v += __shfl_xor(v, 16); v += __shfl_xor(v, 32);
      if (lane < 16) atomicAdd(&Cs[nBase + wn + j * 16 + lane], v);
    }
  }
}

// out[C,R] = bf16(in[R,C]^T), f32 in. blockIdx.z selects the (in,out) pair.
__global__ void transpose2_f32_bf16(const float* __restrict__ in1, const float* __restrict__ in2,
                                    bf16* __restrict__ out1, bf16* __restrict__ out2, int R, int C)
{
  const float* in = blockIdx.z ? in2 : in1;
  bf16* out = blockIdx.z ? out2 : out1;
  __shared__ float tile[32][33];
  const int bx = blockIdx.x * 32;
  const int by = blockIdx.y * 32;
  const int tx = threadIdx.x & 31, ty = threadIdx.x >> 5;
#pragma unroll
  for (int s = 0; s < 4; s++) {
    int r = ty + s * 8;
    tile[r][tx] = in[(size_t)(by + r) * C + bx + tx];
  }
  __syncthreads();
#pragma unroll
  for (int s = 0; s < 4; s++) {
    int r = ty + s * 8;
    out[(size_t)(bx + r) * R + by + tx] = __float2bfloat16(tile[tx][r]);
  }
}

// elementwise f32 -> bf16, 8 elems/thread, z selects pair
__global__ void convert2_f32_bf16(const float* __restrict__ in1, const float* __restrict__ in2,
                                  bf16* __restrict__ out1, bf16* __restrict__ out2, int n8)
{
  const float* in = blockIdx.z ? in2 : in1;
  bf16* out = blockIdx.z ? out2 : out1;
  const int i = blockIdx.x * 256 + threadIdx.x;
  if (i >= n8) return;
  const size_t off = (size_t)i * 8;
  floatx4 a = *(const floatx4*)(in + off);
  floatx4 b = *(const floatx4*)(in + off + 4);
  short8 r;
#pragma unroll
  for (int j = 0; j < 4; j++) { r[j] = bfbits(a[j]); r[4 + j] = bfbits(b[j]); }
  *(short8*)(out + off) = r;
}

__global__ void zero_f32(float* __restrict__ p, int n)
{
  int i = blockIdx.x * blockDim.x + threadIdx.x;
  if (i < n) p[i] = 0.f;
}

// one wave per row: n = h / max(||h||, 1e-12), rows of 256; z selects view
__global__ void norm_rows2(const bf16* __restrict__ h1, const bf16* __restrict__ h2,
                           bf16* __restrict__ o1, bf16* __restrict__ o2)
{
  const bf16* h = blockIdx.z ? h2 : h1;
  bf16* o = blockIdx.z ? o2 : o1;
  const int row = blockIdx.x * 4 + (threadIdx.x >> 6);
  const int lane = threadIdx.x & 63;
  float v[4]; float ss = 0.f;
#pragma unroll
  for (int j = 0; j < 4; j++) {
    v[j] = __bfloat162float(h[(size_t)row * 256 + lane * 4 + j]);
    ss += v[j] * v[j];
  }
  for (int m = 1; m < 64; m <<= 1) ss += __shfl_xor(ss, m);
  const float s = 1.0f / fmaxf(sqrtf(ss), 1e-12f);
#pragma unroll
  for (int j = 0; j < 4; j++)
    o[(size_t)row * 256 + lane * 4 + j] = __float2bfloat16(v[j] * s);
}

__global__ void loss_partial(const bf16* __restrict__ n1, const bf16* __restrict__ n2,
                             const float* __restrict__ R11, const float* __restrict__ R12,
                             const float* __restrict__ R22, const float* __restrict__ C12,
                             float* __restrict__ lossAcc)
{
  const int row = blockIdx.x * 4 + (threadIdx.x >> 6);
  const int lane = threadIdx.x & 63;
  float d12 = 0.f, d11 = 0.f, d22 = 0.f;
#pragma unroll
  for (int j = 0; j < 4; j++) {
    float a = __bfloat162float(n1[(size_t)row * 256 + lane * 4 + j]);
    float b = __bfloat162float(n2[(size_t)row * 256 + lane * 4 + j]);
    d12 += a * b; d11 += a * a; d22 += b * b;
  }
  for (int m = 1; m < 64; m <<= 1) {
    d12 += __shfl_xor(d12, m); d11 += __shfl_xor(d11, m); d22 += __shfl_xor(d22, m);
  }
  if (lane == 0) {
    float a1 = fmaxf(R11[row] + R12[row] - __expf(2.f * d11), 1e-20f);
    float a2 = fmaxf(R22[row] + C12[row] - __expf(2.f * d22), 1e-20f);
    float l1 = logf(a1) - 2.f * d12;
    float l2 = logf(a2) - 2.f * d12;
    atomicAdd(lossAcc, 0.8f * l1 + 0.2f * l2);
  }
}

__global__ void finalize_loss(const float* __restrict__ lossAcc, float* __restrict__ out)
{
  if (threadIdx.x == 0) out[0] = *lossAcc;
}

extern "C" void kernel_launch(void* const* d_in, const int* in_sizes, int n_in,
                              void* d_out, int out_size, void* d_ws, size_t ws_size,
                              hipStream_t stream)
{
  (void)in_sizes; (void)n_in; (void)out_size;
  const float* x1   = (const float*)d_in[0];
  const float* adj1 = (const float*)d_in[1];
  const float* x2   = (const float*)d_in[2];
  const float* adj2 = (const float*)d_in[3];
  const float* W1a  = (const float*)d_in[4];  const float* b1a = (const float*)d_in[5];
  const float* W1b  = (const float*)d_in[6];  const float* b1b = (const float*)d_in[7];
  const float* W2a  = (const float*)d_in[8];  const float* b2a = (const float*)d_in[9];
  const float* W2b  = (const float*)d_in[10]; const float* b2b = (const float*)d_in[11];
  const float* fc1w = (const float*)d_in[12]; const float* fc1b = (const float*)d_in[13];
  const float* fc11w= (const float*)d_in[14]; const float* fc11b= (const float*)d_in[15];
  const float* fc12w= (const float*)d_in[16]; const float* fc12b= (const float*)d_in[17];
  const float* fc2w = (const float*)d_in[18]; const float* fc2b = (const float*)d_in[19];
  const float* fc3w = (const float*)d_in[20]; const float* fc3b = (const float*)d_in[21];

  float* z1 = (float*)d_out;                        // [4096,2048] f32
  float* z2 = z1 + (size_t)4096 * 2048;
  float* lossOut = z1 + (size_t)2 * 4096 * 2048;    // [1]

  // Workspace (base ~70 MiB, aliased as before). Optional tiers above 70 MiB:
  //  [72,104M):  adjB1   [104,136M): adjB2   (bf16 adj; used if ws >= 136M)
  //  [136,168M): xB1     [168,200M): xB2     (bf16 x;   used if ws >= 200M)
  const size_t MB = 1u << 20;
  char* w = (char*)d_ws;
  bf16* WT1  = (bf16*)(w);
  bf16* WT2  = (bf16*)(w + 8 * MB);
  bf16* TT1  = (bf16*)(w + 16 * MB);
  bf16* TT2  = (bf16*)(w + 24 * MB);
  bf16* zB1  = (bf16*)(w + 32 * MB);
  bf16* zB2  = (bf16*)(w + 48 * MB);
  bf16* fc1T = (bf16*)(w + 64 * MB);
  bf16* fc11T= (bf16*)(w + 68 * MB);
  bf16* fc12T= (bf16*)(w + 69 * MB);
  bf16* fc2T = (bf16*)(w + 69 * MB + 256 * 1024);
  bf16* fc3T = (bf16*)(w + 69 * MB + 512 * 1024);
  float* R11 = (float*)(w + 69 * MB + 768 * 1024);
  float* R12 = R11 + 4096;
  float* R22 = R12 + 4096;
  float* C12 = R22 + 4096;
  float* lossAcc = C12 + 4096;
  // projection-chain aliases
  bf16* P1_1 = (bf16*)(w);
  bf16* P1_2 = (bf16*)(w + 8 * MB);
  bf16* P2_1 = (bf16*)(w + 16 * MB);
  bf16* P2_2 = (bf16*)(w + 20 * MB);
  bf16* P3_1 = (bf16*)(w + 24 * MB);
  bf16* P3_2 = (bf16*)(w + 26 * MB);
  bf16* P4_1 = (bf16*)(w + 28 * MB);
  bf16* P4_2 = (bf16*)(w);
  bf16* Hp1  = (bf16*)(w + 4 * MB);
  bf16* Hp2  = (bf16*)(w + 6 * MB);
  bf16* n1   = (bf16*)(w + 8 * MB);
  bf16* n2   = (bf16*)(w + 10 * MB);
  // bf16-converted inputs (tiered on ws_size; bit-identical math vs AF32 path)
  bf16* adjB1 = (bf16*)(w + 72 * MB);
  bf16* adjB2 = (bf16*)(w + 104 * MB);
  bf16* xB1   = (bf16*)(w + 136 * MB);
  bf16* xB2   = (bf16*)(w + 168 * MB);
  const bool cvtAdj = ws_size >= 136 * MB;
  const bool cvtX   = ws_size >= 200 * MB;

  dim3 blk(256);

  zero_f32<<<dim3(65), blk, 0, stream>>>(R11, 4 * 4096 + 1);

  // pre-convert f32 inputs to bf16 (enables global_load_lds path + halves A fetch)
  if (cvtAdj)
    convert2_f32_bf16<<<dim3(8192, 1, 2), blk, 0, stream>>>(adj1, adj2, adjB1, adjB2, 2097152);
  if (cvtX)
    convert2_f32_bf16<<<dim3(8192, 1, 2), blk, 0, stream>>>(x1, x2, xB1, xB2, 2097152);

  // projection-head weight transposes (shared by both views; z=1)
  transpose2_f32_bf16<<<dim3(32, 64, 1), blk, 0, stream>>>(fc1w, fc1w, fc1T, fc1T, 2048, 1024);
  transpose2_f32_bf16<<<dim3(16, 32, 1), blk, 0, stream>>>(fc11w, fc11w, fc11T, fc11T, 1024, 512);
  transpose2_f32_bf16<<<dim3(8, 16, 1),  blk, 0, stream>>>(fc12w, fc12w, fc12T, fc12T, 512, 256);
  transpose2_f32_bf16<<<dim3(16, 8, 1),  blk, 0, stream>>>(fc2w, fc2w, fc2T, fc2T, 256, 512);
  transpose2_f32_bf16<<<dim3(8, 16, 1),  blk, 0, stream>>>(fc3w, fc3w, fc3T, fc3T, 512, 256);

  // h1 = leaky(G @ (x @ Wa + ba)) — both views fused per launch
  transpose2_f32_bf16<<<dim3(32, 128, 2), blk, 0, stream>>>(W1a, W2a, WT1, WT2, 4096, 1024);
  if (cvtX)
    gemm_bt<0, 1, 1, 0, 0, 0><<<dim3(8, 32, 2), blk, 0, stream>>>(
        xB1, xB2, 4096, WT1, WT2, 4096, b1a, b2a, TT1, TT2, nullptr, nullptr, 4096, 4096);
  else
    gemm_bt<0, 1, 1, 1, 0, 0><<<dim3(8, 32, 2), blk, 0, stream>>>(
        x1, x2, 4096, WT1, WT2, 4096, b1a, b2a, TT1, TT2, nullptr, nullptr, 4096, 4096);
  if (cvtAdj)
    gemm_bt<1, 0, 0, 0, 1, 1><<<dim3(8, 32, 2), blk, 0, stream>>>(
        adjB1, adjB2, 4096, TT1, TT2, 4096, nullptr, nullptr, z1, z2, zB1, zB2, 2048, 4096);
  else
    gemm_bt<1, 0, 0, 1, 1, 1><<<dim3(8, 32, 2), blk, 0, stream>>>(
        adj1, adj2, 4096, TT1, TT2, 4096, nullptr, nullptr, z1, z2, zB1, zB2, 2048, 4096);
  // h2 = leaky(G @ (h1 @ Wb + bb))
  transpose2_f32_bf16<<<dim3(32, 32, 2), blk, 0, stream>>>(W1b, W2b, WT1, WT2, 1024, 1024);
  gemm_bt<0, 1, 1, 0, 0, 0><<<dim3(8, 32, 2), blk, 0, stream>>>(
      zB1, zB2, 2048, WT1, WT2, 1024, b1b, b2b, TT1, TT2, nullptr, nullptr, 4096, 1024);
  if (cvtAdj)
    gemm_bt<1, 0, 0, 0, 1, 1><<<dim3(8, 32, 2), blk, 0, stream>>>(
        adjB1, adjB2, 4096, TT1, TT2, 4096, nullptr, nullptr, z1 + 1024, z2 + 1024, zB1 + 1024, zB2 + 1024, 2048, 4096);
  else
    gemm_bt<1, 0, 0, 1, 1, 1><<<dim3(8, 32, 2), blk, 0, stream>>>(
        adj1, adj2, 4096, TT1, TT2, 4096, nullptr, nullptr, z1 + 1024, z2 + 1024, zB1 + 1024, zB2 + 1024, 2048, 4096);

  // projection head (weights shared across views)
  gemm_bt<2, 0, 1, 0, 0, 0><<<dim3(8, 32, 2), blk, 0, stream>>>(
      zB1, zB2, 2048, fc1T, fc1T, 2048, fc1b, fc1b, P1_1, P1_2, nullptr, nullptr, 1024, 2048);
  gemm_bt<2, 0, 1, 0, 0, 0><<<dim3(4, 32, 2), blk, 0, stream>>>(
      P1_1, P1_2, 1024, fc11T, fc11T, 1024, fc11b, fc11b, P2_1, P2_2, nullptr, nullptr, 512, 1024);
  gemm_bt<2, 0, 1, 0, 0, 0><<<dim3(2, 32, 2), blk, 0, stream>>>(
      P2_1, P2_2, 512, fc12T, fc12T, 512, fc12b, fc12b, P3_1, P3_2, nullptr, nullptr, 256, 512);
  gemm_bt<2, 0, 1, 0, 0, 0><<<dim3(4, 32, 2), blk, 0, stream>>>(
      P3_1, P3_2, 256, fc2T, fc2T, 256, fc2b, fc2b, P4_1, P4_2, nullptr, nullptr, 512, 256);
  gemm_bt<0, 0, 1, 0, 0, 0><<<dim3(2, 32, 2), blk, 0, stream>>>(
      P4_1, P4_2, 512, fc3T, fc3T, 512, fc3b, fc3b, Hp1, Hp2, nullptr, nullptr, 256, 512);
  norm_rows2<<<dim3(1024, 1, 2), blk, 0, stream>>>(Hp1, Hp2, n1, n2);

  // fused exp-sum reductions of the three similarity matrices
  sim3<<<dim3(32, 32, 3), blk, 0, stream>>>(n1, n2, R11, R22, R12, C12);

  loss_partial<<<dim3(1024), blk, 0, stream>>>(n1, n2, R11, R12, R22, C12, lossAcc);
  finalize_loss<<<dim3(1), dim3(64), 0, stream>>>(lossAcc, lossOut);
}

// Round 3
// 830.947 us; speedup vs baseline: 1.1818x; 1.1310x over previous
//
#include <hip/hip_runtime.h>
#include <hip/hip_bf16.h>
#include <cstdint>

using bf16 = __hip_bfloat16;
typedef __attribute__((ext_vector_type(8))) short short8;
typedef __attribute__((ext_vector_type(4))) short short4v;
typedef __attribute__((ext_vector_type(4))) float floatx4;

#define DEVINL __device__ __forceinline__

DEVINL short bfbits(float v) { return __builtin_bit_cast(short, __float2bfloat16(v)); }

// async global->LDS, 16B per lane. LDS dest must be wave-uniform base + lane*16 (linear).
DEVINL void gload_lds16(const void* g, void* l) {
  __builtin_amdgcn_global_load_lds((const __attribute__((address_space(1))) void*)g,
                                   (__attribute__((address_space(3))) void*)l, 16, 0, 0);
}

template<int ACT> DEVINL float activate(float v) {
  if constexpr (ACT == 1) return v > 0.f ? v : 0.25f * v;            // leaky_relu(0.25)
  else if constexpr (ACT == 2) return v > 0.f ? v : __expf(v) - 1.f; // elu
  else return v;
}

// LDS bank-conflict swizzle (T2, rule #21): tiles are [128 rows][8 slots of 16B].
// Row stride 128B => all lanes of a 16-lane column-read hit one bank quad (16-way).
// XOR the 16B-slot index with (row&7): column reads spread over all 8 quads (2-way, free).
// gload_lds path: LDS dest stays LINEAR; the *global source* slot is inverse-permuted
// (XOR is an involution) so swizzled reads find the right data.
// reg-staged paths: ds_write addr and ds_read addr both XOR'd.

// C[M,N] = A[M,K] * B[N,K]^T (+bias[col]) (+act).  f32 accum, MFMA bf16.
// blockIdx (swizzled) selects view via z, fusing two independent GEMMs.
// AF32: A is float32 -> reg-staged + converted at LDS-write (fallback path).
// !AF32: A,B bf16 -> global_load_lds width-16 double-buffered staging, 1 barrier/K-step.
// TRANS: store C^T (bf16). DUAL (with OF32): also store bf16 C to outB.
template<int ACT, int TRANS, int BIAS, int AF32, int OF32, int DUAL>
__global__ __launch_bounds__(256, 2)
void gemm_bt(const void* __restrict__ A1, const void* __restrict__ A2, int lda,
             const bf16* __restrict__ B1, const bf16* __restrict__ B2, int ldb,
             const float* __restrict__ bias1, const float* __restrict__ bias2,
             void* __restrict__ out1, void* __restrict__ out2,
             bf16* __restrict__ outB1, bf16* __restrict__ outB2,
             int ldo, int K)
{
  // ---- XCD swizzle (bijective; nwg is always a multiple of 8 here) ----
  const int gx = gridDim.x, gy = gridDim.y;
  const int nwg = gx * gy * gridDim.z;
  int bx, by, vz;
  if (nwg & 7) {
    bx = blockIdx.x; by = blockIdx.y; vz = blockIdx.z;
  } else {
    const int flat = blockIdx.x + gx * (blockIdx.y + gy * blockIdx.z);
    const int cpx = nwg >> 3;
    const int w = (flat & 7) * cpx + (flat >> 3);
    bx = w % gx;
    const int tmp = w / gx;
    by = tmp % gy;
    vz = tmp / gy;
  }

  const void* A = vz ? A2 : A1;
  const bf16* B = vz ? B2 : B1;
  const float* bias = vz ? bias2 : bias1;
  void* out = vz ? out2 : out1;
  bf16* outB = vz ? outB2 : outB1;

  constexpr int NBUF = AF32 ? 1 : 2;
  __shared__ bf16 At[NBUF][128 * 64];
  __shared__ bf16 Bt[NBUF][128 * 64];
  const int t = threadIdx.x;
  const int wave = t >> 6, lane = t & 63;
  const int mBase = by * 128, nBase = bx * 128;
  const int wm = (wave >> 1) * 64, wn = (wave & 1) * 64;
  const int q = lane >> 4, lm = lane & 15;
  const int rm = lm & 7;                      // row&7 for all fragment rows this lane reads

  floatx4 acc[4][4];
#pragma unroll
  for (int i = 0; i < 4; i++)
#pragma unroll
    for (int j = 0; j < 4; j++) acc[i][j] = (floatx4){0.f, 0.f, 0.f, 0.f};

  if constexpr (!AF32) {
    // ---- global_load_lds double-buffered staging, pre-swizzled global source ----
    auto STAGE = [&](int buf, int kb) {
#pragma unroll
      for (int i = 0; i < 4; i++) {
        const int c0 = i * 256 + wave * 64;   // wave-uniform LDS base (elements/8)
        const int c = c0 + lane;
        const int row = c >> 3;
        const int ls = (c & 7) ^ (row & 7);   // logical slot landing at this physical slot
        const bf16* ga = (const bf16*)A + (size_t)(mBase + row) * lda + kb + (ls << 3);
        const bf16* gb = B + (size_t)(nBase + row) * ldb + kb + (ls << 3);
        gload_lds16(ga, &At[buf][c0 * 8]);
        gload_lds16(gb, &Bt[buf][c0 * 8]);
      }
    };
    int cur = 0;
    STAGE(0, 0);
    for (int kb = 0; kb < K; kb += 64) {
      __syncthreads();                        // drains vmcnt -> buf[cur] ready; prev readers done
      if (kb + 64 < K) STAGE(cur ^ 1, kb + 64);  // prefetch overlaps MFMA below
#pragma unroll
      for (int ks = 0; ks < 64; ks += 32) {
        const int sl = (ks >> 3) + q;         // logical 16B slot
        short8 af[4], bfr[4];
#pragma unroll
        for (int i = 0; i < 4; i++)
          af[i] = *(const short8*)&At[cur][(wm + i * 16 + lm) * 64 + ((sl ^ rm) << 3)];
#pragma unroll
        for (int j = 0; j < 4; j++)
          bfr[j] = *(const short8*)&Bt[cur][(wn + j * 16 + lm) * 64 + ((sl ^ rm) << 3)];
#pragma unroll
        for (int i = 0; i < 4; i++)
#pragma unroll
          for (int j = 0; j < 4; j++)
            acc[i][j] = __builtin_amdgcn_mfma_f32_16x16x32_bf16(af[i], bfr[j], acc[i][j], 0, 0, 0);
      }
      cur ^= 1;
    }
  } else {
    // ---- fallback: f32 A, reg-staged, convert at LDS-write (swizzled write+read) ----
    floatx4 apl[4], aph[4];
    short8 bpb[4];
    auto LA = [&](int kb) {
#pragma unroll
      for (int i = 0; i < 4; i++) {
        int c = i * 256 + t;
        size_t off = (size_t)(mBase + (c >> 3)) * lda + kb + ((c & 7) << 3);
        const float* f = (const float*)A + off;
        apl[i] = *(const floatx4*)f;
        aph[i] = *(const floatx4*)(f + 4);
      }
    };
    auto LB = [&](int kb) {
#pragma unroll
      for (int i = 0; i < 4; i++) {
        int c = i * 256 + t;
        bpb[i] = *(const short8*)(B + (size_t)(nBase + (c >> 3)) * ldb + kb + ((c & 7) << 3));
      }
    };
    LA(0); LB(0);
    for (int kb = 0; kb < K; kb += 64) {
      __syncthreads();
#pragma unroll
      for (int i = 0; i < 4; i++) {
        int c = i * 256 + t;
        const int row = c >> 3;
        const int ps = (c & 7) ^ (row & 7);   // physical slot for this logical slot
        short8 r;
#pragma unroll
        for (int j = 0; j < 4; j++) { r[j] = bfbits(apl[i][j]); r[4 + j] = bfbits(aph[i][j]); }
        *(short8*)&At[0][row * 64 + (ps << 3)] = r;
        *(short8*)&Bt[0][row * 64 + (ps << 3)] = bpb[i];
      }
      __syncthreads();
      if (kb + 64 < K) { LA(kb + 64); LB(kb + 64); }
#pragma unroll
      for (int ks = 0; ks < 64; ks += 32) {
        const int sl = (ks >> 3) + q;
        short8 af[4], bfr[4];
#pragma unroll
        for (int i = 0; i < 4; i++)
          af[i] = *(const short8*)&At[0][(wm + i * 16 + lm) * 64 + ((sl ^ rm) << 3)];
#pragma unroll
        for (int j = 0; j < 4; j++)
          bfr[j] = *(const short8*)&Bt[0][(wn + j * 16 + lm) * 64 + ((sl ^ rm) << 3)];
#pragma unroll
        for (int i = 0; i < 4; i++)
#pragma unroll
          for (int j = 0; j < 4; j++)
            acc[i][j] = __builtin_amdgcn_mfma_f32_16x16x32_bf16(af[i], bfr[j], acc[i][j], 0, 0, 0);
      }
    }
  }

#pragma unroll
  for (int i = 0; i < 4; i++) {
#pragma unroll
    for (int j = 0; j < 4; j++) {
      const int col = nBase + wn + j * 16 + lm;
      float bv2 = 0.f;
      if constexpr (BIAS) bv2 = bias[col];
      if constexpr (TRANS) {
        short4v pk;
#pragma unroll
        for (int r = 0; r < 4; r++)
          pk[r] = bfbits(activate<ACT>(acc[i][j][r] + bv2));
        const int row = mBase + wm + i * 16 + q * 4;
        *(short4v*)&((bf16*)out)[(size_t)col * ldo + row] = pk;
      } else {
#pragma unroll
        for (int r = 0; r < 4; r++) {
          const int row = mBase + wm + i * 16 + q * 4 + r;
          float v = activate<ACT>(acc[i][j][r] + bv2);
          if constexpr (OF32) ((float*)out)[(size_t)row * ldo + col] = v;
          else ((bf16*)out)[(size_t)row * ldo + col] = __float2bfloat16(v);
          if constexpr (DUAL) outB[(size_t)row * ldo + col] = __float2bfloat16(v);
        }
      }
    }
  }
}

// Fused 3-way sim reduction: blockIdx.z = 0:(n1,n1->R11) 1:(n2,n2->R22) 2:(n1,n2->R12,C12).
__global__ __launch_bounds__(256, 2)
void sim3(const bf16* __restrict__ n1, const bf16* __restrict__ n2,
          float* __restrict__ R11, float* __restrict__ R22,
          float* __restrict__ R12, float* __restrict__ C12)
{
  const bf16 *A, *B; float *Rs, *Cs;
  if (blockIdx.z == 0)      { A = n1; B = n1; Rs = R11; Cs = nullptr; }
  else if (blockIdx.z == 1) { A = n2; B = n2; Rs = R22; Cs = nullptr; }
  else                      { A = n1; B = n2; Rs = R12; Cs = C12; }

  __shared__ bf16 At[128 * 64];
  __shared__ bf16 Bt[128 * 64];
  const int t = threadIdx.x;
  const int wave = t >> 6, lane = t & 63;
  const int mBase = blockIdx.y * 128, nBase = blockIdx.x * 128;
  const int wm = (wave >> 1) * 64, wn = (wave & 1) * 64;
  const int q = lane >> 4, lm = lane & 15;
  const int rm = lm & 7;

  floatx4 acc[4][4];
#pragma unroll
  for (int i = 0; i < 4; i++)
#pragma unroll
    for (int j = 0; j < 4; j++) acc[i][j] = (floatx4){0.f, 0.f, 0.f, 0.f};

  short8 apb[4], bpb[4];
  auto LD = [&](int kb) {
#pragma unroll
    for (int i = 0; i < 4; i++) {
      int c = i * 256 + t;
      apb[i] = *(const short8*)(A + (size_t)(mBase + (c >> 3)) * 256 + kb + ((c & 7) << 3));
      bpb[i] = *(const short8*)(B + (size_t)(nBase + (c >> 3)) * 256 + kb + ((c & 7) << 3));
    }
  };

  LD(0);
  for (int kb = 0; kb < 256; kb += 64) {
    __syncthreads();
#pragma unroll
    for (int i = 0; i < 4; i++) {
      int c = i * 256 + t;
      const int row = c >> 3;
      const int ps = (c & 7) ^ (row & 7);
      *(short8*)&At[row * 64 + (ps << 3)] = apb[i];
      *(short8*)&Bt[row * 64 + (ps << 3)] = bpb[i];
    }
    __syncthreads();
    if (kb + 64 < 256) LD(kb + 64);
#pragma unroll
    for (int ks = 0; ks < 64; ks += 32) {
      const int sl = (ks >> 3) + q;
      short8 af[4], bfr[4];
#pragma unroll
      for (int i = 0; i < 4; i++)
        af[i] = *(const short8*)&At[(wm + i * 16 + lm) * 64 + ((sl ^ rm) << 3)];
#pragma unroll
      for (int j = 0; j < 4; j++)
        bfr[j] = *(const short8*)&Bt[(wn + j * 16 + lm) * 64 + ((sl ^ rm) << 3)];
#pragma unroll
      for (int i = 0; i < 4; i++)
#pragma unroll
        for (int j = 0; j < 4; j++)
          acc[i][j] = __builtin_amdgcn_mfma_f32_16x16x32_bf16(af[i], bfr[j], acc[i][j], 0, 0, 0);
    }
  }

  float rs[4][4], cs[4];
#pragma unroll
  for (int i = 0; i < 4; i++) { cs[i] = 0.f;
#pragma unroll
    for (int r = 0; r < 4; r++) rs[i][r] = 0.f; }

#pragma unroll
  for (int i = 0; i < 4; i++)
#pragma unroll
    for (int j = 0; j < 4; j++)
#pragma unroll
      for (int r = 0; r < 4; r++) {
        float e = __expf(2.f * acc[i][j][r]);   // 1/TAU = 2
        rs[i][r] += e;
        cs[j] += e;
      }

#pragma unroll
  for (int i = 0; i < 4; i++)
#pragma unroll
    for (int r = 0; r < 4; r++) {
      float v = rs[i][r];
      v += __shfl_xor(v, 1); v += __shfl_xor(v, 2);
      v += __shfl_xor(v, 4); v += __shfl_xor(v, 8);
      if (lm == 0) atomicAdd(&Rs[mBase + wm + i * 16 + q * 4 + r], v);
    }
  if (Cs) {
#pragma unroll
    for (int j = 0; j < 4; j++) {
      float v = cs[j];
      v += __shfl_xor(v, 16); v += __shfl_xor(v, 32);
      if (lane < 16) atomicAdd(&Cs[nBase + wn + j * 16 + lane], v);
    }
  }
}

// out[C,R] = bf16(in[R,C]^T), f32 in. blockIdx.z selects the (in,out) pair.
__global__ void transpose2_f32_bf16(const float* __restrict__ in1, const float* __restrict__ in2,
                                    bf16* __restrict__ out1, bf16* __restrict__ out2, int R, int C)
{
  const float* in = blockIdx.z ? in2 : in1;
  bf16* out = blockIdx.z ? out2 : out1;
  __shared__ float tile[32][33];
  const int bx = blockIdx.x * 32;
  const int by = blockIdx.y * 32;
  const int tx = threadIdx.x & 31, ty = threadIdx.x >> 5;
#pragma unroll
  for (int s = 0; s < 4; s++) {
    int r = ty + s * 8;
    tile[r][tx] = in[(size_t)(by + r) * C + bx + tx];
  }
  __syncthreads();
#pragma unroll
  for (int s = 0; s < 4; s++) {
    int r = ty + s * 8;
    out[(size_t)(bx + r) * R + by + tx] = __float2bfloat16(tile[tx][r]);
  }
}

// elementwise f32 -> bf16, 8 elems/thread, z selects pair
__global__ void convert2_f32_bf16(const float* __restrict__ in1, const float* __restrict__ in2,
                                  bf16* __restrict__ out1, bf16* __restrict__ out2, int n8)
{
  const float* in = blockIdx.z ? in2 : in1;
  bf16* out = blockIdx.z ? out2 : out1;
  const int i = blockIdx.x * 256 + threadIdx.x;
  if (i >= n8) return;
  const size_t off = (size_t)i * 8;
  floatx4 a = *(const floatx4*)(in + off);
  floatx4 b = *(const floatx4*)(in + off + 4);
  short8 r;
#pragma unroll
  for (int j = 0; j < 4; j++) { r[j] = bfbits(a[j]); r[4 + j] = bfbits(b[j]); }
  *(short8*)(out + off) = r;
}

__global__ void zero_f32(float* __restrict__ p, int n)
{
  int i = blockIdx.x * blockDim.x + threadIdx.x;
  if (i < n) p[i] = 0.f;
}

// one wave per row: n = h / max(||h||, 1e-12), rows of 256; z selects view
__global__ void norm_rows2(const bf16* __restrict__ h1, const bf16* __restrict__ h2,
                           bf16* __restrict__ o1, bf16* __restrict__ o2)
{
  const bf16* h = blockIdx.z ? h2 : h1;
  bf16* o = blockIdx.z ? o2 : o1;
  const int row = blockIdx.x * 4 + (threadIdx.x >> 6);
  const int lane = threadIdx.x & 63;
  float v[4]; float ss = 0.f;
#pragma unroll
  for (int j = 0; j < 4; j++) {
    v[j] = __bfloat162float(h[(size_t)row * 256 + lane * 4 + j]);
    ss += v[j] * v[j];
  }
  for (int m = 1; m < 64; m <<= 1) ss += __shfl_xor(ss, m);
  const float s = 1.0f / fmaxf(sqrtf(ss), 1e-12f);
#pragma unroll
  for (int j = 0; j < 4; j++)
    o[(size_t)row * 256 + lane * 4 + j] = __float2bfloat16(v[j] * s);
}

__global__ void loss_partial(const bf16* __restrict__ n1, const bf16* __restrict__ n2,
                             const float* __restrict__ R11, const float* __restrict__ R12,
                             const float* __restrict__ R22, const float* __restrict__ C12,
                             float* __restrict__ lossAcc)
{
  const int row = blockIdx.x * 4 + (threadIdx.x >> 6);
  const int lane = threadIdx.x & 63;
  float d12 = 0.f, d11 = 0.f, d22 = 0.f;
#pragma unroll
  for (int j = 0; j < 4; j++) {
    float a = __bfloat162float(n1[(size_t)row * 256 + lane * 4 + j]);
    float b = __bfloat162float(n2[(size_t)row * 256 + lane * 4 + j]);
    d12 += a * b; d11 += a * a; d22 += b * b;
  }
  for (int m = 1; m < 64; m <<= 1) {
    d12 += __shfl_xor(d12, m); d11 += __shfl_xor(d11, m); d22 += __shfl_xor(d22, m);
  }
  if (lane == 0) {
    float a1 = fmaxf(R11[row] + R12[row] - __expf(2.f * d11), 1e-20f);
    float a2 = fmaxf(R22[row] + C12[row] - __expf(2.f * d22), 1e-20f);
    float l1 = logf(a1) - 2.f * d12;
    float l2 = logf(a2) - 2.f * d12;
    atomicAdd(lossAcc, 0.8f * l1 + 0.2f * l2);
  }
}

__global__ void finalize_loss(const float* __restrict__ lossAcc, float* __restrict__ out)
{
  if (threadIdx.x == 0) out[0] = *lossAcc;
}

extern "C" void kernel_launch(void* const* d_in, const int* in_sizes, int n_in,
                              void* d_out, int out_size, void* d_ws, size_t ws_size,
                              hipStream_t stream)
{
  (void)in_sizes; (void)n_in; (void)out_size;
  const float* x1   = (const float*)d_in[0];
  const float* adj1 = (const float*)d_in[1];
  const float* x2   = (const float*)d_in[2];
  const float* adj2 = (const float*)d_in[3];
  const float* W1a  = (const float*)d_in[4];  const float* b1a = (const float*)d_in[5];
  const float* W1b  = (const float*)d_in[6];  const float* b1b = (const float*)d_in[7];
  const float* W2a  = (const float*)d_in[8];  const float* b2a = (const float*)d_in[9];
  const float* W2b  = (const float*)d_in[10]; const float* b2b = (const float*)d_in[11];
  const float* fc1w = (const float*)d_in[12]; const float* fc1b = (const float*)d_in[13];
  const float* fc11w= (const float*)d_in[14]; const float* fc11b= (const float*)d_in[15];
  const float* fc12w= (const float*)d_in[16]; const float* fc12b= (const float*)d_in[17];
  const float* fc2w = (const float*)d_in[18]; const float* fc2b = (const float*)d_in[19];
  const float* fc3w = (const float*)d_in[20]; const float* fc3b = (const float*)d_in[21];

  float* z1 = (float*)d_out;                        // [4096,2048] f32
  float* z2 = z1 + (size_t)4096 * 2048;
  float* lossOut = z1 + (size_t)2 * 4096 * 2048;    // [1]

  // Workspace (base ~70 MiB, aliased as before). Optional tiers above 70 MiB:
  //  [72,104M):  adjB1   [104,136M): adjB2   (bf16 adj; used if ws >= 136M)
  //  [136,168M): xB1     [168,200M): xB2     (bf16 x;   used if ws >= 200M)
  const size_t MB = 1u << 20;
  char* w = (char*)d_ws;
  bf16* WT1  = (bf16*)(w);
  bf16* WT2  = (bf16*)(w + 8 * MB);
  bf16* TT1  = (bf16*)(w + 16 * MB);
  bf16* TT2  = (bf16*)(w + 24 * MB);
  bf16* zB1  = (bf16*)(w + 32 * MB);
  bf16* zB2  = (bf16*)(w + 48 * MB);
  bf16* fc1T = (bf16*)(w + 64 * MB);
  bf16* fc11T= (bf16*)(w + 68 * MB);
  bf16* fc12T= (bf16*)(w + 69 * MB);
  bf16* fc2T = (bf16*)(w + 69 * MB + 256 * 1024);
  bf16* fc3T = (bf16*)(w + 69 * MB + 512 * 1024);
  float* R11 = (float*)(w + 69 * MB + 768 * 1024);
  float* R12 = R11 + 4096;
  float* R22 = R12 + 4096;
  float* C12 = R22 + 4096;
  float* lossAcc = C12 + 4096;
  // projection-chain aliases
  bf16* P1_1 = (bf16*)(w);
  bf16* P1_2 = (bf16*)(w + 8 * MB);
  bf16* P2_1 = (bf16*)(w + 16 * MB);
  bf16* P2_2 = (bf16*)(w + 20 * MB);
  bf16* P3_1 = (bf16*)(w + 24 * MB);
  bf16* P3_2 = (bf16*)(w + 26 * MB);
  bf16* P4_1 = (bf16*)(w + 28 * MB);
  bf16* P4_2 = (bf16*)(w);
  bf16* Hp1  = (bf16*)(w + 4 * MB);
  bf16* Hp2  = (bf16*)(w + 6 * MB);
  bf16* n1   = (bf16*)(w + 8 * MB);
  bf16* n2   = (bf16*)(w + 10 * MB);
  // bf16-converted inputs (tiered on ws_size; bit-identical math vs AF32 path)
  bf16* adjB1 = (bf16*)(w + 72 * MB);
  bf16* adjB2 = (bf16*)(w + 104 * MB);
  bf16* xB1   = (bf16*)(w + 136 * MB);
  bf16* xB2   = (bf16*)(w + 168 * MB);
  const bool cvtAdj = ws_size >= 136 * MB;
  const bool cvtX   = ws_size >= 200 * MB;

  dim3 blk(256);

  zero_f32<<<dim3(65), blk, 0, stream>>>(R11, 4 * 4096 + 1);

  // pre-convert f32 inputs to bf16 (enables global_load_lds path + halves A fetch)
  if (cvtAdj)
    convert2_f32_bf16<<<dim3(8192, 1, 2), blk, 0, stream>>>(adj1, adj2, adjB1, adjB2, 2097152);
  if (cvtX)
    convert2_f32_bf16<<<dim3(8192, 1, 2), blk, 0, stream>>>(x1, x2, xB1, xB2, 2097152);

  // projection-head weight transposes (shared by both views; z=1)
  transpose2_f32_bf16<<<dim3(32, 64, 1), blk, 0, stream>>>(fc1w, fc1w, fc1T, fc1T, 2048, 1024);
  transpose2_f32_bf16<<<dim3(16, 32, 1), blk, 0, stream>>>(fc11w, fc11w, fc11T, fc11T, 1024, 512);
  transpose2_f32_bf16<<<dim3(8, 16, 1),  blk, 0, stream>>>(fc12w, fc12w, fc12T, fc12T, 512, 256);
  transpose2_f32_bf16<<<dim3(16, 8, 1),  blk, 0, stream>>>(fc2w, fc2w, fc2T, fc2T, 256, 512);
  transpose2_f32_bf16<<<dim3(8, 16, 1),  blk, 0, stream>>>(fc3w, fc3w, fc3T, fc3T, 512, 256);

  // h1 = leaky(G @ (x @ Wa + ba)) — both views fused per launch
  transpose2_f32_bf16<<<dim3(32, 128, 2), blk, 0, stream>>>(W1a, W2a, WT1, WT2, 4096, 1024);
  if (cvtX)
    gemm_bt<0, 1, 1, 0, 0, 0><<<dim3(8, 32, 2), blk, 0, stream>>>(
        xB1, xB2, 4096, WT1, WT2, 4096, b1a, b2a, TT1, TT2, nullptr, nullptr, 4096, 4096);
  else
    gemm_bt<0, 1, 1, 1, 0, 0><<<dim3(8, 32, 2), blk, 0, stream>>>(
        x1, x2, 4096, WT1, WT2, 4096, b1a, b2a, TT1, TT2, nullptr, nullptr, 4096, 4096);
  if (cvtAdj)
    gemm_bt<1, 0, 0, 0, 1, 1><<<dim3(8, 32, 2), blk, 0, stream>>>(
        adjB1, adjB2, 4096, TT1, TT2, 4096, nullptr, nullptr, z1, z2, zB1, zB2, 2048, 4096);
  else
    gemm_bt<1, 0, 0, 1, 1, 1><<<dim3(8, 32, 2), blk, 0, stream>>>(
        adj1, adj2, 4096, TT1, TT2, 4096, nullptr, nullptr, z1, z2, zB1, zB2, 2048, 4096);
  // h2 = leaky(G @ (h1 @ Wb + bb))
  transpose2_f32_bf16<<<dim3(32, 32, 2), blk, 0, stream>>>(W1b, W2b, WT1, WT2, 1024, 1024);
  gemm_bt<0, 1, 1, 0, 0, 0><<<dim3(8, 32, 2), blk, 0, stream>>>(
      zB1, zB2, 2048, WT1, WT2, 1024, b1b, b2b, TT1, TT2, nullptr, nullptr, 4096, 1024);
  if (cvtAdj)
    gemm_bt<1, 0, 0, 0, 1, 1><<<dim3(8, 32, 2), blk, 0, stream>>>(
        adjB1, adjB2, 4096, TT1, TT2, 4096, nullptr, nullptr, z1 + 1024, z2 + 1024, zB1 + 1024, zB2 + 1024, 2048, 4096);
  else
    gemm_bt<1, 0, 0, 1, 1, 1><<<dim3(8, 32, 2), blk, 0, stream>>>(
        adj1, adj2, 4096, TT1, TT2, 4096, nullptr, nullptr, z1 + 1024, z2 + 1024, zB1 + 1024, zB2 + 1024, 2048, 4096);

  // projection head (weights shared across views)
  gemm_bt<2, 0, 1, 0, 0, 0><<<dim3(8, 32, 2), blk, 0, stream>>>(
      zB1, zB2, 2048, fc1T, fc1T, 2048, fc1b, fc1b, P1_1, P1_2, nullptr, nullptr, 1024, 2048);
  gemm_bt<2, 0, 1, 0, 0, 0><<<dim3(4, 32, 2), blk, 0, stream>>>(
      P1_1, P1_2, 1024, fc11T, fc11T, 1024, fc11b, fc11b, P2_1, P2_2, nullptr, nullptr, 512, 1024);
  gemm_bt<2, 0, 1, 0, 0, 0><<<dim3(2, 32, 2), blk, 0, stream>>>(
      P2_1, P2_2, 512, fc12T, fc12T, 512, fc12b, fc12b, P3_1, P3_2, nullptr, nullptr, 256, 512);
  gemm_bt<2, 0, 1, 0, 0, 0><<<dim3(4, 32, 2), blk, 0, stream>>>(
      P3_1, P3_2, 256, fc2T, fc2T, 256, fc2b, fc2b, P4_1, P4_2, nullptr, nullptr, 512, 256);
  gemm_bt<0, 0, 1, 0, 0, 0><<<dim3(2, 32, 2), blk, 0, stream>>>(
      P4_1, P4_2, 512, fc3T, fc3T, 512, fc3b, fc3b, Hp1, Hp2, nullptr, nullptr, 256, 512);
  norm_rows2<<<dim3(1024, 1, 2), blk, 0, stream>>>(Hp1, Hp2, n1, n2);

  // fused exp-sum reductions of the three similarity matrices
  sim3<<<dim3(32, 32, 3), blk, 0, stream>>>(n1, n2, R11, R22, R12, C12);

  loss_partial<<<dim3(1024), blk, 0, stream>>>(n1, n2, R11, R12, R22, C12, lossAcc);
  finalize_loss<<<dim3(1), dim3(64), 0, stream>>>(lossAcc, lossOut);
}